// Round 2
// baseline (759.873 us; speedup 1.0000x reference)
//
#include <hip/hip_runtime.h>
#include <math.h>

#define TPB   256
#define CIN   64
#define CHID  16
#define COUT  64
#define BB    4
#define HH    352
#define WW    1216
#define HW_   (HH * WW)            // 428,032
#define MTOT  (BB * HW_)           // 1,712,128
#define NCOPY 32                   // spread copies for stats atomics
#define WTILES (WW / 64)           // 19

// ---------------------------------------------------------------------------
// ws layout: [winner int[MTOT]] [pix int[N]] [stats float[NCOPY*128]] [count int]
// ---------------------------------------------------------------------------

__global__ __launch_bounds__(TPB) void k_init(int* __restrict__ winner,
                                              float* __restrict__ statsf,
                                              int* __restrict__ count) {
    int i = blockIdx.x * TPB + threadIdx.x;
    if (i < MTOT) winner[i] = -1;
    if (i < NCOPY * 128) statsf[i] = 0.0f;
    if (i == 0) *count = 0;
}

// Projection in STRICT float32 (numpy einsum semantics: per-product rounding,
// left-to-right f32 accumulation, no FMA contraction) to match the np
// reference's floor/clip bins bit-for-bit.
__global__ __launch_bounds__(TPB) void k_project(const float* __restrict__ pos,
                                                 const int* __restrict__ batch,
                                                 const float* __restrict__ cam,
                                                 int N,
                                                 int* __restrict__ winner,
                                                 int* __restrict__ pixarr) {
    int n = blockIdx.x * TPB + threadIdx.x;
    if (n >= N) return;
    int b = batch[n];
    const float* Km = cam + b * 9;
    float x = pos[3 * n + 0];
    float y = pos[3 * n + 1];
    float z = pos[3 * n + 2];
    // p_i = ((K[i][0]*x + K[i][1]*y) + K[i][2]*z), each op individually rounded
    float p0 = __fadd_rn(__fadd_rn(__fmul_rn(Km[0], x), __fmul_rn(Km[1], y)),
                         __fmul_rn(Km[2], z));
    float p1 = __fadd_rn(__fadd_rn(__fmul_rn(Km[3], x), __fmul_rn(Km[4], y)),
                         __fmul_rn(Km[5], z));
    float p2 = __fadd_rn(__fadd_rn(__fmul_rn(Km[6], x), __fmul_rn(Km[7], y)),
                         __fmul_rn(Km[8], z));
    float u = __fdiv_rn(p0, p2);
    float v = __fdiv_rn(p1, p2);
    float uf = fminf(fmaxf(floorf(u), 0.0f), (float)(WW - 1));
    float vf = fminf(fmaxf(floorf(v), 0.0f), (float)(HH - 1));
    int ui = (int)uf;
    int vi = (int)vf;
    int p = b * HW_ + vi * WW + ui;
    pixarr[n] = p;
    atomicMax(&winner[p], n);   // numpy last-index-wins == max n
}

// Per-channel sum / sumsq over winner-point features, plus winner count.
__global__ __launch_bounds__(TPB) void k_stats(const float* __restrict__ feat,
        const float* __restrict__ W1, const float* __restrict__ b1,
        const float* __restrict__ W2, const float* __restrict__ b2,
        const int* __restrict__ winner, const int* __restrict__ pixarr,
        int N, float* __restrict__ statsf, int* __restrict__ count) {
    __shared__ float W1s[CIN * CHID];
    __shared__ float W2s[CHID * COUT];
    __shared__ float b1s[CHID];
    __shared__ float b2s[COUT];
    __shared__ float hid_s[TPB * 17];   // +1 pad breaks bank conflicts
    __shared__ float act_s[TPB];

    int t = threadIdx.x;
    for (int i = t; i < CIN * CHID; i += TPB) W1s[i] = W1[i];
    for (int i = t; i < CHID * COUT; i += TPB) W2s[i] = W2[i];
    if (t < CHID) b1s[t] = b1[t];
    if (t < COUT) b2s[t] = b2[t];
    __syncthreads();

    int n = blockIdx.x * TPB + t;
    bool active = false;
    if (n < N) active = (winner[pixarr[n]] == n);

    unsigned long long mb = __ballot(active);
    if ((t & 63) == 0) atomicAdd(count, (int)__popcll(mb));

    float hloc[CHID];
#pragma unroll
    for (int h = 0; h < CHID; h++) hloc[h] = 0.0f;
    if (active) {
#pragma unroll
        for (int h = 0; h < CHID; h++) hloc[h] = b1s[h];
        const float4* X = (const float4*)(feat + (size_t)n * CIN);
#pragma unroll
        for (int j = 0; j < 16; j++) {
            float4 x4 = X[j];
            const float* w = &W1s[4 * j * CHID];
#pragma unroll
            for (int h = 0; h < CHID; h++) {
                float acc = hloc[h];
                acc = fmaf(x4.x, w[h], acc);
                acc = fmaf(x4.y, w[CHID + h], acc);
                acc = fmaf(x4.z, w[2 * CHID + h], acc);
                acc = fmaf(x4.w, w[3 * CHID + h], acc);
                hloc[h] = acc;
            }
        }
#pragma unroll
        for (int h = 0; h < CHID; h++) hloc[h] = fmaxf(hloc[h], 0.0f);
    }
#pragma unroll
    for (int h = 0; h < CHID; h++) hid_s[t * 17 + h] = hloc[h];
    act_s[t] = active ? 1.0f : 0.0f;
    __syncthreads();

    // channel-parallel: lane handles channel c, group g covers 64 points.
    int c = t & 63;
    int g = t >> 6;
    float s = 0.0f, q = 0.0f;
    for (int i = 0; i < 64; i++) {
        int p = g * 64 + i;
        float a = act_s[p];                 // wave-uniform (broadcast)
        float f = b2s[c];
#pragma unroll
        for (int h = 0; h < CHID; h++)
            f = fmaf(hid_s[p * 17 + h], W2s[h * COUT + c], f);
        float fa = f * a;
        s += fa;
        q = fmaf(fa, f, q);
    }
    float* dst = statsf + (blockIdx.x & (NCOPY - 1)) * 128;
    atomicAdd(&dst[c], s);
    atomicAdd(&dst[64 + c], q);
}

// Output: per 64-pixel tile, finalize BN params, gather winner features,
// recompute MLP via LDS hidden tile, write coalesced [B,C,H,W].
__global__ __launch_bounds__(TPB) void k_out(const float* __restrict__ feat,
        const float* __restrict__ W1, const float* __restrict__ b1,
        const float* __restrict__ W2, const float* __restrict__ b2,
        const float* __restrict__ zenc, const float* __restrict__ gmm,
        const float* __restrict__ bta, const int* __restrict__ winner,
        const float* __restrict__ statsf, const int* __restrict__ count,
        float* __restrict__ out) {
    __shared__ float W1s[CIN * CHID];
    __shared__ float W2s[CHID * COUT];
    __shared__ float b1s[CHID];
    __shared__ float b2s[COUT];
    __shared__ float scale_s[COUT], shift_s[COUT], empty_s[COUT];
    __shared__ float hid_s[64 * 17];
    __shared__ int   n_s[64];

    int t = threadIdx.x;
    int blk = blockIdx.x;
    int wt = blk % WTILES;
    int hh = (blk / WTILES) % HH;
    int bb = blk / (WTILES * HH);
    int w0 = wt * 64;
    int pix0 = bb * HW_ + hh * WW + w0;

    for (int i = t; i < CIN * CHID; i += TPB) W1s[i] = W1[i];
    for (int i = t; i < CHID * COUT; i += TPB) W2s[i] = W2[i];
    if (t < CHID) b1s[t] = b1[t];
    if (t < COUT) b2s[t] = b2[t];
    if (t < 64) {
        float s = 0.0f, q = 0.0f;
        for (int g = 0; g < NCOPY; g++) {
            s += statsf[g * 128 + t];
            q += statsf[g * 128 + 64 + t];
        }
        float Kc = (float)(*count);
        const float Mf = (float)MTOT;
        float zc = zenc[t];
        float mean = (s + (Mf - Kc) * zc) / Mf;
        float e2   = (q + (Mf - Kc) * zc * zc) / Mf;
        float var  = e2 - mean * mean;
        float inv  = 1.0f / sqrtf(var + 1e-5f);
        float sc = gmm[t] * inv;
        float sh = bta[t] - mean * sc;
        scale_s[t] = sc;
        shift_s[t] = sh;
        empty_s[t] = fmaf(zc, sc, sh);
        n_s[t] = winner[pix0 + t];
    }
    __syncthreads();

    // Phase B: hidden[16] per pixel; wave g computes h-quarter g for all 64 pixels.
    {
        int p  = t & 63;
        int h0 = (t >> 6) * 4;
        int n  = n_s[p];
        float a0 = 0.0f, a1 = 0.0f, a2 = 0.0f, a3 = 0.0f;
        if (n >= 0) {
            a0 = b1s[h0]; a1 = b1s[h0 + 1]; a2 = b1s[h0 + 2]; a3 = b1s[h0 + 3];
            const float4* X = (const float4*)(feat + (size_t)n * CIN);
#pragma unroll
            for (int j = 0; j < 16; j++) {
                float4 x4 = X[j];
                const float* w = &W1s[4 * j * CHID + h0];
                a0 = fmaf(x4.x, w[0], a0);
                a1 = fmaf(x4.x, w[1], a1);
                a2 = fmaf(x4.x, w[2], a2);
                a3 = fmaf(x4.x, w[3], a3);
                a0 = fmaf(x4.y, w[CHID + 0], a0);
                a1 = fmaf(x4.y, w[CHID + 1], a1);
                a2 = fmaf(x4.y, w[CHID + 2], a2);
                a3 = fmaf(x4.y, w[CHID + 3], a3);
                a0 = fmaf(x4.z, w[2 * CHID + 0], a0);
                a1 = fmaf(x4.z, w[2 * CHID + 1], a1);
                a2 = fmaf(x4.z, w[2 * CHID + 2], a2);
                a3 = fmaf(x4.z, w[2 * CHID + 3], a3);
                a0 = fmaf(x4.w, w[3 * CHID + 0], a0);
                a1 = fmaf(x4.w, w[3 * CHID + 1], a1);
                a2 = fmaf(x4.w, w[3 * CHID + 2], a2);
                a3 = fmaf(x4.w, w[3 * CHID + 3], a3);
            }
            a0 = fmaxf(a0, 0.0f);
            a1 = fmaxf(a1, 0.0f);
            a2 = fmaxf(a2, 0.0f);
            a3 = fmaxf(a3, 0.0f);
        }
        hid_s[p * 17 + h0 + 0] = a0;
        hid_s[p * 17 + h0 + 1] = a1;
        hid_s[p * 17 + h0 + 2] = a2;
        hid_s[p * 17 + h0 + 3] = a3;
    }
    __syncthreads();

    // Phase C: wave c0 writes channels {c0, c0+4, ...}; stores are contiguous 256B.
    {
        int p  = t & 63;
        int c0 = t >> 6;
        int n  = n_s[p];
        float hr[CHID];
#pragma unroll
        for (int h = 0; h < CHID; h++) hr[h] = hid_s[p * 17 + h];
        size_t ob = (((size_t)bb * COUT) * HH + hh) * (size_t)WW + w0 + p;
#pragma unroll
        for (int k = 0; k < 16; k++) {
            int c = c0 + 4 * k;
            float val;
            if (n >= 0) {
                float f = b2s[c];
#pragma unroll
                for (int h = 0; h < CHID; h++)
                    f = fmaf(hr[h], W2s[h * COUT + c], f);
                val = fmaf(f, scale_s[c], shift_s[c]);
            } else {
                val = empty_s[c];
            }
            out[ob + (size_t)c * HW_] = val;
        }
    }
}

extern "C" void kernel_launch(void* const* d_in, const int* in_sizes, int n_in,
                              void* d_out, int out_size, void* d_ws, size_t ws_size,
                              hipStream_t stream) {
    const float* feat  = (const float*)d_in[0];
    const float* pos   = (const float*)d_in[1];
    const int*   batch = (const int*)d_in[2];
    const float* cam   = (const float*)d_in[3];
    const float* W1    = (const float*)d_in[4];
    const float* b1    = (const float*)d_in[5];
    const float* W2    = (const float*)d_in[6];
    const float* b2    = (const float*)d_in[7];
    const float* zenc  = (const float*)d_in[8];
    const float* gmm   = (const float*)d_in[9];
    const float* bta   = (const float*)d_in[10];
    int N = in_sizes[2];

    int*   winner = (int*)d_ws;
    int*   pixarr = winner + MTOT;
    float* statsf = (float*)(pixarr + N);
    int*   count  = (int*)(statsf + NCOPY * 128);
    float* outp   = (float*)d_out;

    k_init<<<(MTOT + TPB - 1) / TPB, TPB, 0, stream>>>(winner, statsf, count);
    k_project<<<(N + TPB - 1) / TPB, TPB, 0, stream>>>(pos, batch, cam, N, winner, pixarr);
    k_stats<<<(N + TPB - 1) / TPB, TPB, 0, stream>>>(feat, W1, b1, W2, b2,
                                                     winner, pixarr, N, statsf, count);
    k_out<<<BB * HH * WTILES, TPB, 0, stream>>>(feat, W1, b1, W2, b2, zenc, gmm, bta,
                                                winner, statsf, count, outp);
}

// Round 3
// 676.081 us; speedup vs baseline: 1.1239x; 1.1239x over previous
//
#include <hip/hip_runtime.h>
#include <math.h>

#define TPB   256
#define CIN   64
#define CHID  16
#define COUT  64
#define BB    4
#define HH    352
#define WW    1216
#define HW_   (HH * WW)            // 428,032
#define MTOT  (BB * HW_)           // 1,712,128
#define NCOPY 32
#define WTILES (WW / 64)           // 19
#define NTILES (BB * HH * WTILES)  // 26,752
#define KS_BLOCKS 768              // k_sums blocks (3072 waves)

// ---------------------------------------------------------------------------
// ws layout (int32 units): winner[MTOT] | pixarr[N] | statsf[NCOPY*128] |
//                          misc[4] (count at [0]) | hid[N*16] | w2tp[1024] |
//                          biasp[64] | emptyv[64]
// All segment lengths divisible by 4 -> float4 alignment holds throughout.
// ---------------------------------------------------------------------------

__global__ __launch_bounds__(TPB) void k_init(int4* __restrict__ winner4,
                                              float4* __restrict__ statsf4,
                                              int* __restrict__ count) {
    int g = blockIdx.x * TPB + threadIdx.x;
    if (g < MTOT / 4) winner4[g] = make_int4(-1, -1, -1, -1);
    if (g < (NCOPY * 128) / 4) statsf4[g] = make_float4(0.f, 0.f, 0.f, 0.f);
    if (g == 0) *count = 0;
}

// Projection in STRICT float32 (numpy einsum semantics) — bit-exact bins vs np.
__global__ __launch_bounds__(TPB) void k_project(const float* __restrict__ pos,
                                                 const int* __restrict__ batch,
                                                 const float* __restrict__ cam,
                                                 int N,
                                                 int* __restrict__ winner,
                                                 int* __restrict__ pixarr) {
    int n = blockIdx.x * TPB + threadIdx.x;
    if (n >= N) return;
    int b = batch[n];
    const float* Km = cam + b * 9;
    float x = pos[3 * n + 0];
    float y = pos[3 * n + 1];
    float z = pos[3 * n + 2];
    float p0 = __fadd_rn(__fadd_rn(__fmul_rn(Km[0], x), __fmul_rn(Km[1], y)),
                         __fmul_rn(Km[2], z));
    float p1 = __fadd_rn(__fadd_rn(__fmul_rn(Km[3], x), __fmul_rn(Km[4], y)),
                         __fmul_rn(Km[5], z));
    float p2 = __fadd_rn(__fadd_rn(__fmul_rn(Km[6], x), __fmul_rn(Km[7], y)),
                         __fmul_rn(Km[8], z));
    float u = __fdiv_rn(p0, p2);
    float v = __fdiv_rn(p1, p2);
    float uf = fminf(fmaxf(floorf(u), 0.0f), (float)(WW - 1));
    float vf = fminf(fmaxf(floorf(v), 0.0f), (float)(HH - 1));
    int ui = (int)uf;
    int vi = (int)vf;
    int p = b * HW_ + vi * WW + ui;
    pixarr[n] = p;
    atomicMax(&winner[p], n);   // numpy last-index-wins == max n
}

// hid[n][0:16] = relu(feat[n] @ W1 + b1) for winner points, zeros otherwise.
// W1 accessed at wave-uniform addresses -> scalar loads, no LDS.
__global__ __launch_bounds__(TPB) void k_hid(const float* __restrict__ feat,
        const float* __restrict__ W1, const float* __restrict__ b1,
        const int* __restrict__ winner, const int* __restrict__ pixarr,
        int N, float* __restrict__ hidw, int* __restrict__ count) {
    int n = blockIdx.x * TPB + threadIdx.x;
    if (n >= N) return;
    bool active = (winner[pixarr[n]] == n);
    unsigned long long mb = __ballot(active);
    if ((threadIdx.x & 63) == 0) atomicAdd(count, (int)__popcll(mb));

    float h[CHID];
#pragma unroll
    for (int k = 0; k < CHID; k++) h[k] = b1[k];          // uniform
    const float4* X = (const float4*)(feat + (size_t)n * CIN);
    const float4* W14 = (const float4*)W1;                // row j = 4 float4
#pragma unroll
    for (int j4 = 0; j4 < 16; j4++) {
        float4 x4 = X[j4];
#pragma unroll
        for (int e = 0; e < 4; e++) {
            int j = 4 * j4 + e;
            float xj = (e == 0) ? x4.x : (e == 1) ? x4.y : (e == 2) ? x4.z : x4.w;
#pragma unroll
            for (int m = 0; m < 4; m++) {
                float4 w = W14[j * 4 + m];                // uniform
                h[4 * m + 0] = fmaf(xj, w.x, h[4 * m + 0]);
                h[4 * m + 1] = fmaf(xj, w.y, h[4 * m + 1]);
                h[4 * m + 2] = fmaf(xj, w.z, h[4 * m + 2]);
                h[4 * m + 3] = fmaf(xj, w.w, h[4 * m + 3]);
            }
        }
    }
    float4* Ho = (float4*)(hidw + (size_t)n * CHID);
#pragma unroll
    for (int m = 0; m < 4; m++) {
        float4 o;
        o.x = active ? fmaxf(h[4 * m + 0], 0.f) : 0.f;
        o.y = active ? fmaxf(h[4 * m + 1], 0.f) : 0.f;
        o.z = active ? fmaxf(h[4 * m + 2], 0.f) : 0.f;
        o.w = active ? fmaxf(h[4 * m + 3], 0.f) : 0.f;
        Ho[m] = o;
    }
}

// Per-channel S1 = sum(g), S2 = sum(g^2), g = hid . W2[:,c]. Inactive rows are
// zero so they contribute nothing. hid rows read at wave-uniform addresses.
__global__ __launch_bounds__(TPB) void k_sums(const float* __restrict__ hidw,
        const float* __restrict__ W2, int N, float* __restrict__ statsf) {
    int c = threadIdx.x & 63;
    int wv = blockIdx.x * (TPB / 64) + (threadIdx.x >> 6);
    wv = __builtin_amdgcn_readfirstlane(wv);
    float w2c[CHID];
#pragma unroll
    for (int h = 0; h < CHID; h++) w2c[h] = W2[h * COUT + c];  // coalesced
    const int TW = KS_BLOCKS * (TPB / 64);
    int chunk = (N + TW - 1) / TW;
    int i0 = wv * chunk;
    int i1 = min(N, i0 + chunk);
    float s = 0.f, q = 0.f;
    for (int i = i0; i < i1; i++) {
        const float4* Hp = (const float4*)(hidw + (size_t)i * CHID);  // uniform
        float g = 0.f;
#pragma unroll
        for (int m = 0; m < 4; m++) {
            float4 hv = Hp[m];
            g = fmaf(hv.x, w2c[4 * m + 0], g);
            g = fmaf(hv.y, w2c[4 * m + 1], g);
            g = fmaf(hv.z, w2c[4 * m + 2], g);
            g = fmaf(hv.w, w2c[4 * m + 3], g);
        }
        s += g;
        q = fmaf(g, g, q);
    }
    float* dst = statsf + (wv & (NCOPY - 1)) * 128;
    atomicAdd(&dst[c], s);
    atomicAdd(&dst[64 + c], q);
}

// Finalize BN params; fold BN scale into transposed W2 and bias.
__global__ __launch_bounds__(64) void k_finalize(const float* __restrict__ statsf,
        const int* __restrict__ count, const float* __restrict__ W2,
        const float* __restrict__ b2, const float* __restrict__ zenc,
        const float* __restrict__ gmm, const float* __restrict__ bta,
        float* __restrict__ w2tp, float* __restrict__ biasp,
        float* __restrict__ emptyv) {
    int c = threadIdx.x;  // 0..63
    float S1 = 0.f, S2 = 0.f;
    for (int g = 0; g < NCOPY; g++) {
        S1 += statsf[g * 128 + c];
        S2 += statsf[g * 128 + 64 + c];
    }
    float K = (float)(*count);
    float b2c = b2[c];
    float sumf  = K * b2c + S1;
    float sumsq = fmaf(K * b2c, b2c, fmaf(2.f * b2c, S1, S2));
    const float Mf = (float)MTOT;
    float zc = zenc[c];
    float mean = (sumf + (Mf - K) * zc) / Mf;
    float e2   = (sumsq + (Mf - K) * zc * zc) / Mf;
    float var  = e2 - mean * mean;
    float inv  = 1.0f / sqrtf(var + 1e-5f);
    float sc = gmm[c] * inv;
    float sh = bta[c] - mean * sc;
    emptyv[c] = fmaf(zc, sc, sh);
    biasp[c]  = fmaf(b2c, sc, sh);
    for (int h = 0; h < CHID; h++) w2tp[c * CHID + h] = W2[h * COUT + c] * sc;
}

// One wave per 64-pixel tile; lane = pixel. Gather 64B hid rows, 16->64 MLP
// with BN folded into w2tp/biasp (wave-uniform scalar loads), coalesced stores.
__global__ __launch_bounds__(TPB) void k_out(const float* __restrict__ hidw,
        const int* __restrict__ winner, const float* __restrict__ w2tp,
        const float* __restrict__ biasp, const float* __restrict__ emptyv,
        float* __restrict__ out) {
    int tile = blockIdx.x * (TPB / 64) + (threadIdx.x >> 6);
    tile = __builtin_amdgcn_readfirstlane(tile);
    int p = threadIdx.x & 63;
    int wt  = tile % WTILES;
    int rem = tile / WTILES;
    int hh  = rem % HH;
    int bb  = rem / HH;
    int pix0 = bb * HW_ + hh * WW + wt * 64;

    int n = winner[pix0 + p];
    bool act = (n >= 0);
    size_t nn = act ? (size_t)n : 0;
    const float4* Hp = (const float4*)(hidw + nn * CHID);
    float4 h0 = Hp[0], h1 = Hp[1], h2 = Hp[2], h3 = Hp[3];

    float* ob = out + (size_t)bb * ((size_t)COUT * HW_) + (size_t)hh * WW + wt * 64 + p;
    const float4* W4 = (const float4*)w2tp;
#pragma unroll 4
    for (int c = 0; c < COUT; c++) {
        float4 wa = W4[c * 4 + 0];               // uniform
        float4 wb = W4[c * 4 + 1];
        float4 wc = W4[c * 4 + 2];
        float4 wd = W4[c * 4 + 3];
        float f = biasp[c];                      // uniform
        f = fmaf(h0.x, wa.x, f); f = fmaf(h0.y, wa.y, f);
        f = fmaf(h0.z, wa.z, f); f = fmaf(h0.w, wa.w, f);
        f = fmaf(h1.x, wb.x, f); f = fmaf(h1.y, wb.y, f);
        f = fmaf(h1.z, wb.z, f); f = fmaf(h1.w, wb.w, f);
        f = fmaf(h2.x, wc.x, f); f = fmaf(h2.y, wc.y, f);
        f = fmaf(h2.z, wc.z, f); f = fmaf(h2.w, wc.w, f);
        f = fmaf(h3.x, wd.x, f); f = fmaf(h3.y, wd.y, f);
        f = fmaf(h3.z, wd.z, f); f = fmaf(h3.w, wd.w, f);
        float ev = emptyv[c];                    // uniform
        ob[(size_t)c * HW_] = act ? f : ev;
    }
}

extern "C" void kernel_launch(void* const* d_in, const int* in_sizes, int n_in,
                              void* d_out, int out_size, void* d_ws, size_t ws_size,
                              hipStream_t stream) {
    const float* feat  = (const float*)d_in[0];
    const float* pos   = (const float*)d_in[1];
    const int*   batch = (const int*)d_in[2];
    const float* cam   = (const float*)d_in[3];
    const float* W1    = (const float*)d_in[4];
    const float* b1    = (const float*)d_in[5];
    const float* W2    = (const float*)d_in[6];
    const float* b2    = (const float*)d_in[7];
    const float* zenc  = (const float*)d_in[8];
    const float* gmm   = (const float*)d_in[9];
    const float* bta   = (const float*)d_in[10];
    int N = in_sizes[2];

    int*   winner = (int*)d_ws;
    int*   pixarr = winner + MTOT;
    float* statsf = (float*)(pixarr + N);
    int*   misc   = (int*)(statsf + NCOPY * 128);
    float* hidw   = (float*)(misc + 4);
    float* w2tp   = hidw + (size_t)N * CHID;
    float* biasp  = w2tp + COUT * CHID;
    float* emptyv = biasp + COUT;
    int*   count  = misc;
    float* outp   = (float*)d_out;

    k_init<<<MTOT / 4 / TPB, TPB, 0, stream>>>((int4*)winner, (float4*)statsf, count);
    k_project<<<(N + TPB - 1) / TPB, TPB, 0, stream>>>(pos, batch, cam, N, winner, pixarr);
    k_hid<<<(N + TPB - 1) / TPB, TPB, 0, stream>>>(feat, W1, b1, winner, pixarr, N, hidw, count);
    k_sums<<<KS_BLOCKS, TPB, 0, stream>>>(hidw, W2, N, statsf);
    k_finalize<<<1, 64, 0, stream>>>(statsf, count, W2, b2, zenc, gmm, bta,
                                     w2tp, biasp, emptyv);
    k_out<<<NTILES / (TPB / 64), TPB, 0, stream>>>(hidw, winner, w2tp, biasp, emptyv, outp);
}

// Round 4
// 669.422 us; speedup vs baseline: 1.1351x; 1.0099x over previous
//
#include <hip/hip_runtime.h>
#include <math.h>

#define TPB   256
#define CIN   64
#define CHID  16
#define COUT  64
#define BB    4
#define HH    352
#define WW    1216
#define HW_   (HH * WW)            // 428,032
#define MTOT  (BB * HW_)           // 1,712,128
#define NCOPY 32
#define WTILES (WW / 64)           // 19
#define NTILES (BB * HH * WTILES)  // 26,752
#define KS_BLOCKS 768              // k_sums blocks (3072 waves)

typedef float f32x4 __attribute__((ext_vector_type(4)));

// ---------------------------------------------------------------------------
// ws layout (int32 units): winner[MTOT] | pixarr[N] | statsf[NCOPY*128] |
//   misc[4] (count at [0]) | hidb[N*8] (bf16x2-packed hid, 32B/row) |
//   w2tp[1024] | biasp[64] | emptyv[64]
// ---------------------------------------------------------------------------

__device__ __forceinline__ unsigned bf16rne(float x) {
    unsigned u = __float_as_uint(x);
    return (u + 0x7fffu + ((u >> 16) & 1u)) >> 16;   // RNE; hid is finite
}
__device__ __forceinline__ float bflo(unsigned u) { return __uint_as_float(u << 16); }
__device__ __forceinline__ float bfhi(unsigned u) { return __uint_as_float(u & 0xffff0000u); }

__global__ __launch_bounds__(TPB) void k_init(int4* __restrict__ winner4,
                                              float4* __restrict__ statsf4,
                                              int* __restrict__ count) {
    int g = blockIdx.x * TPB + threadIdx.x;
    if (g < MTOT / 4) winner4[g] = make_int4(-1, -1, -1, -1);
    if (g < (NCOPY * 128) / 4) statsf4[g] = make_float4(0.f, 0.f, 0.f, 0.f);
    if (g == 0) *count = 0;
}

// Projection in STRICT float32 (numpy einsum semantics) — bit-exact bins vs np.
__global__ __launch_bounds__(TPB) void k_project(const float* __restrict__ pos,
                                                 const int* __restrict__ batch,
                                                 const float* __restrict__ cam,
                                                 int N,
                                                 int* __restrict__ winner,
                                                 int* __restrict__ pixarr) {
    int n = blockIdx.x * TPB + threadIdx.x;
    if (n >= N) return;
    int b = batch[n];
    const float* Km = cam + b * 9;
    float x = pos[3 * n + 0];
    float y = pos[3 * n + 1];
    float z = pos[3 * n + 2];
    float p0 = __fadd_rn(__fadd_rn(__fmul_rn(Km[0], x), __fmul_rn(Km[1], y)),
                         __fmul_rn(Km[2], z));
    float p1 = __fadd_rn(__fadd_rn(__fmul_rn(Km[3], x), __fmul_rn(Km[4], y)),
                         __fmul_rn(Km[5], z));
    float p2 = __fadd_rn(__fadd_rn(__fmul_rn(Km[6], x), __fmul_rn(Km[7], y)),
                         __fmul_rn(Km[8], z));
    float u = __fdiv_rn(p0, p2);
    float v = __fdiv_rn(p1, p2);
    float uf = fminf(fmaxf(floorf(u), 0.0f), (float)(WW - 1));
    float vf = fminf(fmaxf(floorf(v), 0.0f), (float)(HH - 1));
    int ui = (int)uf;
    int vi = (int)vf;
    int p = b * HW_ + vi * WW + ui;
    pixarr[n] = p;
    atomicMax(&winner[p], n);   // numpy last-index-wins == max n
}

// hid[n] = relu(feat[n] @ W1 + b1) for winners, zeros otherwise; bf16-packed.
// W1 accesses wave-uniform -> scalar loads; feat streamed non-temporally.
__global__ __launch_bounds__(TPB) void k_hid(const float* __restrict__ feat,
        const float* __restrict__ W1, const float* __restrict__ b1,
        const int* __restrict__ winner, const int* __restrict__ pixarr,
        int N, unsigned* __restrict__ hidb, int* __restrict__ count) {
    int n = blockIdx.x * TPB + threadIdx.x;
    if (n >= N) return;
    bool active = (winner[pixarr[n]] == n);
    unsigned long long mb = __ballot(active);
    if ((threadIdx.x & 63) == 0) atomicAdd(count, (int)__popcll(mb));

    float h[CHID];
#pragma unroll
    for (int k = 0; k < CHID; k++) h[k] = b1[k];          // uniform
    const f32x4* X = (const f32x4*)(feat + (size_t)n * CIN);
    const f32x4* W14 = (const f32x4*)W1;
#pragma unroll
    for (int j4 = 0; j4 < 16; j4++) {
        f32x4 x4 = __builtin_nontemporal_load(&X[j4]);
#pragma unroll
        for (int e = 0; e < 4; e++) {
            int j = 4 * j4 + e;
            float xj = x4[e];
#pragma unroll
            for (int m = 0; m < 4; m++) {
                f32x4 w = W14[j * 4 + m];                 // uniform
                h[4 * m + 0] = fmaf(xj, w[0], h[4 * m + 0]);
                h[4 * m + 1] = fmaf(xj, w[1], h[4 * m + 1]);
                h[4 * m + 2] = fmaf(xj, w[2], h[4 * m + 2]);
                h[4 * m + 3] = fmaf(xj, w[3], h[4 * m + 3]);
            }
        }
    }
#pragma unroll
    for (int k = 0; k < CHID; k++) h[k] = active ? fmaxf(h[k], 0.f) : 0.f;
    uint4 o0, o1;
    o0.x = bf16rne(h[0])  | (bf16rne(h[1])  << 16);
    o0.y = bf16rne(h[2])  | (bf16rne(h[3])  << 16);
    o0.z = bf16rne(h[4])  | (bf16rne(h[5])  << 16);
    o0.w = bf16rne(h[6])  | (bf16rne(h[7])  << 16);
    o1.x = bf16rne(h[8])  | (bf16rne(h[9])  << 16);
    o1.y = bf16rne(h[10]) | (bf16rne(h[11]) << 16);
    o1.z = bf16rne(h[12]) | (bf16rne(h[13]) << 16);
    o1.w = bf16rne(h[14]) | (bf16rne(h[15]) << 16);
    uint4* Ho = (uint4*)(hidb + (size_t)n * 8);
    Ho[0] = o0;
    Ho[1] = o1;
}

// Per-channel S1 = sum(g), S2 = sum(g^2), g = hid . W2[:,c]. Inactive rows are
// zero. hid rows read at wave-uniform addresses -> scalar loads.
__global__ __launch_bounds__(TPB) void k_sums(const unsigned* __restrict__ hidb,
        const float* __restrict__ W2, int N, float* __restrict__ statsf) {
    int c = threadIdx.x & 63;
    int wv = blockIdx.x * (TPB / 64) + (threadIdx.x >> 6);
    wv = __builtin_amdgcn_readfirstlane(wv);
    float w2c[CHID];
#pragma unroll
    for (int h = 0; h < CHID; h++) w2c[h] = W2[h * COUT + c];  // coalesced
    const int TW = KS_BLOCKS * (TPB / 64);
    int chunk = (N + TW - 1) / TW;
    int i0 = wv * chunk;
    int i1 = min(N, i0 + chunk);
    float s = 0.f, q = 0.f;
    for (int i = i0; i < i1; i++) {
        const uint4* Hp = (const uint4*)(hidb + (size_t)i * 8);   // uniform
        uint4 A = Hp[0], B = Hp[1];
        float g = 0.f;
        g = fmaf(bflo(A.x), w2c[0],  g); g = fmaf(bfhi(A.x), w2c[1],  g);
        g = fmaf(bflo(A.y), w2c[2],  g); g = fmaf(bfhi(A.y), w2c[3],  g);
        g = fmaf(bflo(A.z), w2c[4],  g); g = fmaf(bfhi(A.z), w2c[5],  g);
        g = fmaf(bflo(A.w), w2c[6],  g); g = fmaf(bfhi(A.w), w2c[7],  g);
        g = fmaf(bflo(B.x), w2c[8],  g); g = fmaf(bfhi(B.x), w2c[9],  g);
        g = fmaf(bflo(B.y), w2c[10], g); g = fmaf(bfhi(B.y), w2c[11], g);
        g = fmaf(bflo(B.z), w2c[12], g); g = fmaf(bfhi(B.z), w2c[13], g);
        g = fmaf(bflo(B.w), w2c[14], g); g = fmaf(bfhi(B.w), w2c[15], g);
        s += g;
        q = fmaf(g, g, q);
    }
    float* dst = statsf + (wv & (NCOPY - 1)) * 128;
    atomicAdd(&dst[c], s);
    atomicAdd(&dst[64 + c], q);
}

// Finalize BN params; fold BN scale into transposed W2 and bias.
__global__ __launch_bounds__(64) void k_finalize(const float* __restrict__ statsf,
        const int* __restrict__ count, const float* __restrict__ W2,
        const float* __restrict__ b2, const float* __restrict__ zenc,
        const float* __restrict__ gmm, const float* __restrict__ bta,
        float* __restrict__ w2tp, float* __restrict__ biasp,
        float* __restrict__ emptyv) {
    int c = threadIdx.x;  // 0..63
    float S1 = 0.f, S2 = 0.f;
    for (int g = 0; g < NCOPY; g++) {
        S1 += statsf[g * 128 + c];
        S2 += statsf[g * 128 + 64 + c];
    }
    float K = (float)(*count);
    float b2c = b2[c];
    float sumf  = K * b2c + S1;
    float sumsq = fmaf(K * b2c, b2c, fmaf(2.f * b2c, S1, S2));
    const float Mf = (float)MTOT;
    float zc = zenc[c];
    float mean = (sumf + (Mf - K) * zc) / Mf;
    float e2   = (sumsq + (Mf - K) * zc * zc) / Mf;
    float var  = e2 - mean * mean;
    float inv  = 1.0f / sqrtf(var + 1e-5f);
    float sc = gmm[c] * inv;
    float sh = bta[c] - mean * sc;
    emptyv[c] = fmaf(zc, sc, sh);
    biasp[c]  = fmaf(b2c, sc, sh);
    for (int h = 0; h < CHID; h++) w2tp[c * CHID + h] = W2[h * COUT + c] * sc;
}

// One wave per 64-pixel tile; lane = pixel. Gather 32B bf16 hid rows, 16->64
// MLP with BN folded (wave-uniform weight loads), non-temporal coalesced stores.
__global__ __launch_bounds__(TPB) void k_out(const unsigned* __restrict__ hidb,
        const int* __restrict__ winner, const float* __restrict__ w2tp,
        const float* __restrict__ biasp, const float* __restrict__ emptyv,
        float* __restrict__ out) {
    int tile = blockIdx.x * (TPB / 64) + (threadIdx.x >> 6);
    tile = __builtin_amdgcn_readfirstlane(tile);
    int p = threadIdx.x & 63;
    int wt  = tile % WTILES;
    int rem = tile / WTILES;
    int hh  = rem % HH;
    int bb  = rem / HH;
    int pix0 = bb * HW_ + hh * WW + wt * 64;

    int n = winner[pix0 + p];
    bool act = (n >= 0);
    size_t nn = act ? (size_t)n : 0;
    const uint4* Hp = (const uint4*)(hidb + nn * 8);
    uint4 A = Hp[0], B = Hp[1];
    float hv[CHID];
    hv[0]  = bflo(A.x); hv[1]  = bfhi(A.x);
    hv[2]  = bflo(A.y); hv[3]  = bfhi(A.y);
    hv[4]  = bflo(A.z); hv[5]  = bfhi(A.z);
    hv[6]  = bflo(A.w); hv[7]  = bfhi(A.w);
    hv[8]  = bflo(B.x); hv[9]  = bfhi(B.x);
    hv[10] = bflo(B.y); hv[11] = bfhi(B.y);
    hv[12] = bflo(B.z); hv[13] = bfhi(B.z);
    hv[14] = bflo(B.w); hv[15] = bfhi(B.w);

    float* ob = out + (size_t)bb * ((size_t)COUT * HW_) + (size_t)hh * WW + wt * 64 + p;
    const f32x4* W4 = (const f32x4*)w2tp;
#pragma unroll 4
    for (int c = 0; c < COUT; c++) {
        f32x4 wa = W4[c * 4 + 0];               // uniform
        f32x4 wb = W4[c * 4 + 1];
        f32x4 wc = W4[c * 4 + 2];
        f32x4 wd = W4[c * 4 + 3];
        float f = biasp[c];                     // uniform
        f = fmaf(hv[0],  wa[0], f); f = fmaf(hv[1],  wa[1], f);
        f = fmaf(hv[2],  wa[2], f); f = fmaf(hv[3],  wa[3], f);
        f = fmaf(hv[4],  wb[0], f); f = fmaf(hv[5],  wb[1], f);
        f = fmaf(hv[6],  wb[2], f); f = fmaf(hv[7],  wb[3], f);
        f = fmaf(hv[8],  wc[0], f); f = fmaf(hv[9],  wc[1], f);
        f = fmaf(hv[10], wc[2], f); f = fmaf(hv[11], wc[3], f);
        f = fmaf(hv[12], wd[0], f); f = fmaf(hv[13], wd[1], f);
        f = fmaf(hv[14], wd[2], f); f = fmaf(hv[15], wd[3], f);
        float ev = emptyv[c];                   // uniform
        __builtin_nontemporal_store(act ? f : ev, ob + (size_t)c * HW_);
    }
}

extern "C" void kernel_launch(void* const* d_in, const int* in_sizes, int n_in,
                              void* d_out, int out_size, void* d_ws, size_t ws_size,
                              hipStream_t stream) {
    const float* feat  = (const float*)d_in[0];
    const float* pos   = (const float*)d_in[1];
    const int*   batch = (const int*)d_in[2];
    const float* cam   = (const float*)d_in[3];
    const float* W1    = (const float*)d_in[4];
    const float* b1    = (const float*)d_in[5];
    const float* W2    = (const float*)d_in[6];
    const float* b2    = (const float*)d_in[7];
    const float* zenc  = (const float*)d_in[8];
    const float* gmm   = (const float*)d_in[9];
    const float* bta   = (const float*)d_in[10];
    int N = in_sizes[2];

    int*      winner = (int*)d_ws;
    int*      pixarr = winner + MTOT;
    float*    statsf = (float*)(pixarr + N);
    int*      misc   = (int*)(statsf + NCOPY * 128);
    unsigned* hidb   = (unsigned*)(misc + 4);
    float*    w2tp   = (float*)(hidb + (size_t)N * 8);
    float*    biasp  = w2tp + COUT * CHID;
    float*    emptyv = biasp + COUT;
    int*      count  = misc;
    float*    outp   = (float*)d_out;

    k_init<<<MTOT / 4 / TPB, TPB, 0, stream>>>((int4*)winner, (float4*)statsf, count);
    k_project<<<(N + TPB - 1) / TPB, TPB, 0, stream>>>(pos, batch, cam, N, winner, pixarr);
    k_hid<<<(N + TPB - 1) / TPB, TPB, 0, stream>>>(feat, W1, b1, winner, pixarr, N, hidb, count);
    k_sums<<<KS_BLOCKS, TPB, 0, stream>>>(hidb, W2, N, statsf);
    k_finalize<<<1, 64, 0, stream>>>(statsf, count, W2, b2, zenc, gmm, bta,
                                     w2tp, biasp, emptyv);
    k_out<<<NTILES / (TPB / 64), TPB, 0, stream>>>(hidb, winner, w2tp, biasp, emptyv, outp);
}